// Round 1
// baseline (982.335 us; speedup 1.0000x reference)
//
#include <hip/hip_runtime.h>
#include <math.h>

#define T_CHAIN 655360
#define BLK_STEPS 2560
#define NB (T_CHAIN / BLK_STEPS)          // 256
#define STEP_N 10
#define OUT_PER_BLK (BLK_STEPS / STEP_N)  // 256

__device__ __forceinline__ double neg_inf_d() {
    return __longlong_as_double((long long)0xFFF0000000000000LL);
}

// Stable ascending argsort of 64 floats held one-per-lane (wave64 bitonic).
// Returns the ORIGINAL index of the element at sorted position `lane`, i.e. rp[lane].
__device__ __forceinline__ int wave_sort_row(const float* __restrict__ xrow, int lane) {
    unsigned key = __float_as_uint(xrow[lane]);  // x in (1e-6, 1-1e-6): positive -> bit order == value order
    int idx = lane;
#pragma unroll
    for (int k = 2; k <= 64; k <<= 1) {
#pragma unroll
        for (int j = k >> 1; j > 0; j >>= 1) {
            unsigned okey = __shfl_xor(key, j);
            int oidx = __shfl_xor(idx, j);
            int partner = lane ^ j;
            bool up = ((lane & k) == 0);
            bool takeMin = ((lane < partner) == up);
            bool less = (key < okey) || (key == okey && idx < oidx);  // stable tiebreak
            bool keep = (less == takeMin);
            key = keep ? key : okey;
            idx = keep ? idx : oidx;
        }
    }
    return idx;
}

// ---------------- kernel A0: lnu[i] = log(u[i]) in f64 ----------------
__global__ void k_lnu(const float* __restrict__ u, double* __restrict__ lnu, int n) {
    int i = blockIdx.x * blockDim.x + threadIdx.x;
    if (i < n) lnu[i] = log((double)u[i]);  // u==0 -> -inf (accept-always), matches ref
}

// ---------------- kernel A: per-row sort + w + b ----------------
__global__ __launch_bounds__(256) void k_rows(const float* __restrict__ rand_u,
                                              const float* __restrict__ bigram,
                                              const float* __restrict__ startv,
                                              const float* __restrict__ endv,
                                              const double* __restrict__ lnu,
                                              double* __restrict__ w_arr,
                                              double* __restrict__ b_arr) {
    int lane = threadIdx.x & 63;
    int wv = threadIdx.x >> 6;
    int row = blockIdx.x * 4 + wv;
    int rp = wave_sort_row(rand_u + (size_t)row * 64, lane);
    bool gold = (bool)__all(rp == lane);
    int nxt = __shfl_down(rp, 1);
    double dt = 0.0;
    if (lane < 63) dt = (double)bigram[rp * 64 + nxt];  // bigram[rp[k], rp[k+1]]
    if (lane == 0) dt += (double)startv[rp];
    if (lane == 63) dt += (double)endv[rp];
#pragma unroll
    for (int off = 32; off >= 1; off >>= 1) dt += __shfl_xor(dt, off);
    if (lane == 0) {
        w_arr[row] = dt;
        b_arr[row] = gold ? neg_inf_d() : (dt - lnu[row]);
        // accept(i | w_last) == (b_i > w_last); gold rows never accept
    }
}

// ---------------- kernel B: per-block records + per-record replay ----------------
__global__ __launch_bounds__(64) void k_records(const double* __restrict__ w_arr,
                                                const double* __restrict__ b_arr,
                                                double* __restrict__ recb_g,
                                                double* __restrict__ outw_g,
                                                int* __restrict__ outlast_g,
                                                int* __restrict__ meta) {
    int lane = threadIdx.x;
    int bl = blockIdx.x;
    int s0 = bl * BLK_STEPS;
    __shared__ double rec_b[64];
    __shared__ int rec_pos[64];
    double M = neg_inf_d();
    int nrec = 0;
    for (int c = 0; c < BLK_STEPS / 64; ++c) {
        int i = s0 + c * 64 + lane;
        double b = b_arr[i];
        if (i == 0) b = neg_inf_d();  // step 0 is the initial state, never a proposal
        double pm = b;                 // inclusive prefix max across lanes
#pragma unroll
        for (int d = 1; d < 64; d <<= 1) {
            double o = __shfl_up(pm, d);
            if (lane >= d) pm = fmax(pm, o);
        }
        double prev = __shfl_up(pm, 1);
        double thresh = (lane == 0) ? M : fmax(M, prev);
        bool isrec = b > thresh;  // strict prefix-max record
        unsigned long long mk = __ballot(isrec);
        int myoff = __popcll(mk & ((1ull << lane) - 1ull));
        if (isrec) {
            int pos = nrec + myoff;
            if (pos < 64) { rec_b[pos] = b; rec_pos[pos] = i; }
        }
        nrec += __popcll(mk);
        M = fmax(M, __shfl(pm, 63));
    }
    __syncthreads();
    int m = nrec < 64 ? nrec : 64;
    if (lane < m) {
        int r = rec_pos[lane];
        double w = w_arr[r];  // entering record r == accepting it
        int last = r;
        int hi = s0 + BLK_STEPS;
        for (int i = r + 1; i < hi; ++i) {
            double bb = b_arr[i];
            if (bb > w) { w = w_arr[i]; last = i; }
        }
        recb_g[bl * 64 + lane] = rec_b[lane];
        outw_g[bl * 64 + lane] = w;
        outlast_g[bl * 64 + lane] = last;
    }
    if (lane == 0) meta[bl] = nrec;
}

// ---------------- kernel C: sequential composition over blocks (1 wave) ----------------
__global__ __launch_bounds__(64) void k_compose(const double* __restrict__ w_arr,
                                                const double* __restrict__ b_arr,
                                                const double* __restrict__ recb_g,
                                                const double* __restrict__ outw_g,
                                                const int* __restrict__ outlast_g,
                                                const int* __restrict__ meta,
                                                double* __restrict__ bin_w,
                                                int* __restrict__ bin_last) {
    int lane = threadIdx.x;
    // idx0 = first non-gold row (b > -inf)
    int idx0 = 0;
    for (int base = 0; base < T_CHAIN; base += 64) {
        double b = b_arr[base + lane];
        unsigned long long mk = __ballot(b > neg_inf_d());
        if (mk) { idx0 = base + __ffsll((unsigned long long)mk) - 1; break; }
    }
    double wstate = w_arr[0];  // ref: w_last = w[0] regardless of idx0
    int last = idx0;

    double pb[4], pw[4];
    int pl[4], pmv[4];
#pragma unroll
    for (int ph = 0; ph < 4; ++ph) {
        pb[ph] = recb_g[ph * 64 + lane];
        pw[ph] = outw_g[ph * 64 + lane];
        pl[ph] = outlast_g[ph * 64 + lane];
        pmv[ph] = meta[ph];
    }
    for (int base = 0; base < NB; base += 4) {
#pragma unroll
        for (int ph = 0; ph < 4; ++ph) {
            int bl = base + ph;
            if (lane == 0) { bin_w[bl] = wstate; bin_last[bl] = last; }  // incoming state
            int mr = pmv[ph];
            int m = mr < 64 ? mr : 64;
            if (mr > 64) {
                // record-list overflow fallback: serial wave replay (practically never taken)
                for (int c = 0; c < BLK_STEPS / 64; ++c) {
                    int ib = bl * BLK_STEPS + c * 64;
                    int i = ib + lane;
                    double b = b_arr[i];
                    if (i == 0) b = neg_inf_d();
                    double wv2 = w_arr[i];
                    unsigned long long excl = 0;
                    while (true) {
                        unsigned long long cand = __ballot(b > wstate) & ~excl;
                        if (!cand) break;
                        int rel = __ffsll(cand) - 1;
                        excl = ((1ull << rel) << 1) - 1ull;
                        wstate = __shfl(wv2, rel);
                        last = ib + rel;
                    }
                }
            } else {
                unsigned long long mk = __ballot((lane < m) && (pb[ph] > wstate));
                if (mk) {  // first record with b > w_in is the first accept
                    int j = __ffsll(mk) - 1;
                    wstate = __shfl(pw[ph], j);
                    last = __shfl(pl[ph], j);
                }
            }
            int nb2 = bl + 4;  // 4-deep prefetch ring (static addresses)
            if (nb2 < NB) {
                pb[ph] = recb_g[nb2 * 64 + lane];
                pw[ph] = outw_g[nb2 * 64 + lane];
                pl[ph] = outlast_g[nb2 * 64 + lane];
                pmv[ph] = meta[nb2];
            }
        }
    }
}

// ---------------- kernel B3D: per-block replay + output emit ----------------
__global__ __launch_bounds__(256) void k_emit(const float* __restrict__ rand_u,
                                              const double* __restrict__ w_arr,
                                              const double* __restrict__ b_arr,
                                              const double* __restrict__ bin_w,
                                              const int* __restrict__ bin_last,
                                              int* __restrict__ out) {
    __shared__ int ldsL[OUT_PER_BLK];
    int bl = blockIdx.x;
    int lane = threadIdx.x & 63;
    int wv = threadIdx.x >> 6;
    int s0 = bl * BLK_STEPS;
    if (wv == 0) {
        double w = bin_w[bl];
        int last = bin_last[bl];
        for (int c = 0; c < BLK_STEPS / 64; ++c) {
            int ib = s0 + c * 64;
            int i = ib + lane;
            double b = b_arr[i];
            if (i == 0) b = neg_inf_d();
            double wv2 = w_arr[i];
            unsigned long long accmask = 0, excl = 0;
            while (true) {  // iterate accepts within this 64-step chunk (usually 0)
                unsigned long long cand = __ballot(b > w) & ~excl;
                if (!cand) break;
                int rel = __ffsll(cand) - 1;
                excl = ((1ull << rel) << 1) - 1ull;  // decisions <= rel are final
                accmask |= (1ull << rel);
                w = __shfl(wv2, rel);
            }
            unsigned long long upto = accmask & (((1ull << lane) << 1) - 1ull);  // bits 0..lane
            int Lp = upto ? (ib + 63 - __clzll(upto)) : last;
            int r = c * 64 + lane;
            if (r % 10 == 9) ldsL[(r - 9) / 10] = Lp;  // chain[i] sampled at i%10==9
            if (accmask) last = ib + 63 - __clzll(accmask);
        }
    }
    __syncthreads();
    int prevL = -1;
    int perm = 0;
    for (int t = wv * 64; t < wv * 64 + 64; ++t) {
        int L = ldsL[t];
        if (L != prevL) {  // dedup: L is constant over long stretches (~10^2 accepts total)
            perm = wave_sort_row(rand_u + (size_t)L * 64, lane);
            prevL = L;
        }
        out[((size_t)(bl * OUT_PER_BLK + t)) * 64 + lane] = perm;
    }
}

extern "C" void kernel_launch(void* const* d_in, const int* in_sizes, int n_in,
                              void* d_out, int out_size, void* d_ws, size_t ws_size,
                              hipStream_t stream) {
    const float* rand_u = (const float*)d_in[0];
    const float* u      = (const float*)d_in[1];
    const float* bigram = (const float*)d_in[2];
    const float* startv = (const float*)d_in[3];
    const float* endv   = (const float*)d_in[4];
    int* out = (int*)d_out;

    char* ws = (char*)d_ws;
    const size_t SZ_T8 = (size_t)T_CHAIN * 8;  // 5,242,880
    double* w_arr   = (double*)(ws);
    double* b_arr   = (double*)(ws + SZ_T8);
    double* lnu     = (double*)(ws + 2 * SZ_T8);
    double* recb    = (double*)(ws + 3 * SZ_T8);                    // NB*64*8
    double* outw    = (double*)(ws + 3 * SZ_T8 + 131072);           // NB*64*8
    int*    outlast = (int*)   (ws + 3 * SZ_T8 + 262144);           // NB*64*4
    int*    meta    = (int*)   (ws + 3 * SZ_T8 + 327680);           // NB*4
    double* bin_w   = (double*)(ws + 3 * SZ_T8 + 328704);           // NB*8
    int*    bin_last= (int*)   (ws + 3 * SZ_T8 + 330752);           // NB*4
    // total ~16.1 MB of ws

    k_lnu<<<T_CHAIN / 256, 256, 0, stream>>>(u, lnu, T_CHAIN);
    k_rows<<<T_CHAIN / 4, 256, 0, stream>>>(rand_u, bigram, startv, endv, lnu, w_arr, b_arr);
    k_records<<<NB, 64, 0, stream>>>(w_arr, b_arr, recb, outw, outlast, meta);
    k_compose<<<1, 64, 0, stream>>>(w_arr, b_arr, recb, outw, outlast, meta, bin_w, bin_last);
    k_emit<<<NB, 256, 0, stream>>>(rand_u, w_arr, b_arr, bin_w, bin_last, out);
}

// Round 2
// 904.401 us; speedup vs baseline: 1.0862x; 1.0862x over previous
//
#include <hip/hip_runtime.h>
#include <math.h>

#define T_CHAIN 655360
#define BLK_STEPS 2560
#define NB (T_CHAIN / BLK_STEPS)          // 256
#define STEP_N 10
#define OUT_PER_BLK (BLK_STEPS / STEP_N)  // 256

__device__ __forceinline__ double neg_inf_d() {
    return __longlong_as_double((long long)0xFFF0000000000000LL);
}

// ---- lane-XOR transport: DPP for 1/2 (VALU pipe), ds_swizzle for 4/8/16, shfl for 32 ----
template<int J>
__device__ __forceinline__ unsigned xor_u32(unsigned v) {
    if constexpr (J == 1)
        return (unsigned)__builtin_amdgcn_update_dpp(0, (int)v, 0xB1, 0xF, 0xF, true);  // quad_perm [1,0,3,2]
    else if constexpr (J == 2)
        return (unsigned)__builtin_amdgcn_update_dpp(0, (int)v, 0x4E, 0xF, 0xF, true);  // quad_perm [2,3,0,1]
    else if constexpr (J <= 16)
        return (unsigned)__builtin_amdgcn_ds_swizzle((int)v, (J << 10) | 0x1F);         // BitMode xor=J
    else
        return (unsigned)__shfl_xor((int)v, 32);
}

template<int J>
__device__ __forceinline__ unsigned long long xor_u64(unsigned long long v) {
    unsigned lo = xor_u32<J>((unsigned)v);
    unsigned hi = xor_u32<J>((unsigned)(v >> 32));
    return (((unsigned long long)hi) << 32) | lo;
}

template<int J>
__device__ __forceinline__ double dxor(double d) {  // partner's value at lane^J (bit-exact transport)
    return __longlong_as_double((long long)xor_u64<J>((unsigned long long)__double_as_longlong(d)));
}

// one bitonic compare-exchange stage on the packed u64 key
template<int K, int J>
__device__ __forceinline__ void cex(unsigned long long& key, int lane) {
    unsigned long long pk = xor_u64<J>(key);
    bool takeMin = (((lane & J) == 0) == ((lane & K) == 0));
    bool pless = pk < key;                 // keys unique -> never equal
    if (pless == takeMin) key = pk;
}

// Stable ascending argsort of 64 floats held one-per-lane.
// Returns rp[lane] = original index of the element at sorted position `lane`.
__device__ __forceinline__ int wave_sort_row(const float* __restrict__ xrow, int lane) {
    unsigned bits = __float_as_uint(xrow[lane]);  // positive floats: bit order == value order
    unsigned long long key = (((unsigned long long)bits) << 6) | (unsigned)lane;  // stable composite
    cex<2, 1>(key, lane);
    cex<4, 2>(key, lane); cex<4, 1>(key, lane);
    cex<8, 4>(key, lane); cex<8, 2>(key, lane); cex<8, 1>(key, lane);
    cex<16, 8>(key, lane); cex<16, 4>(key, lane); cex<16, 2>(key, lane); cex<16, 1>(key, lane);
    cex<32, 16>(key, lane); cex<32, 8>(key, lane); cex<32, 4>(key, lane); cex<32, 2>(key, lane); cex<32, 1>(key, lane);
    cex<64, 32>(key, lane); cex<64, 16>(key, lane); cex<64, 8>(key, lane); cex<64, 4>(key, lane); cex<64, 2>(key, lane); cex<64, 1>(key, lane);
    return (int)(key & 63u);
}

// ---------------- kernel A: per-row sort + w + b (k_lnu fused) ----------------
__global__ __launch_bounds__(256) void k_rows(const float* __restrict__ rand_u,
                                              const float* __restrict__ bigram,
                                              const float* __restrict__ startv,
                                              const float* __restrict__ endv,
                                              const float* __restrict__ u,
                                              double* __restrict__ w_arr,
                                              double* __restrict__ b_arr) {
    int lane = threadIdx.x & 63;
    int wv = threadIdx.x >> 6;
    int row = blockIdx.x * 4 + wv;
    int rp = wave_sort_row(rand_u + (size_t)row * 64, lane);
    bool gold = (bool)__all(rp == lane);
    int nxt = __shfl_down(rp, 1);
    double dt = 0.0;
    if (lane < 63) dt = (double)bigram[rp * 64 + nxt];  // bigram[rp[k], rp[k+1]]
    if (lane == 0) dt += (double)startv[rp];
    if (lane == 63) dt += (double)endv[rp];
    // xor-tree reduce, SAME pairing order as round-1 (bit-identical w)
    dt += dxor<32>(dt);
    dt += dxor<16>(dt);
    dt += dxor<8>(dt);
    dt += dxor<4>(dt);
    dt += dxor<2>(dt);
    dt += dxor<1>(dt);
    if (lane == 0) {
        w_arr[row] = dt;
        b_arr[row] = gold ? neg_inf_d() : (dt - log((double)u[row]));
        // accept(i | w_last) == (b_i > w_last); gold rows never accept
    }
}

// ---------------- kernel B: per-block records + per-record replay ----------------
__global__ __launch_bounds__(64) void k_records(const double* __restrict__ w_arr,
                                                const double* __restrict__ b_arr,
                                                double* __restrict__ recb_g,
                                                double* __restrict__ outw_g,
                                                int* __restrict__ outlast_g,
                                                int* __restrict__ meta) {
    int lane = threadIdx.x;
    int bl = blockIdx.x;
    int s0 = bl * BLK_STEPS;
    __shared__ double rec_b[64];
    __shared__ int rec_pos[64];
    double M = neg_inf_d();
    int nrec = 0;
    for (int c = 0; c < BLK_STEPS / 64; ++c) {
        int i = s0 + c * 64 + lane;
        double b = b_arr[i];
        if (i == 0) b = neg_inf_d();  // step 0 is the initial state, never a proposal
        double pm = b;                 // inclusive prefix max across lanes
#pragma unroll
        for (int d = 1; d < 64; d <<= 1) {
            double o = __shfl_up(pm, d);
            if (lane >= d) pm = fmax(pm, o);
        }
        double prev = __shfl_up(pm, 1);
        double thresh = (lane == 0) ? M : fmax(M, prev);
        bool isrec = b > thresh;  // strict prefix-max record
        unsigned long long mk = __ballot(isrec);
        int myoff = __popcll(mk & ((1ull << lane) - 1ull));
        if (isrec) {
            int pos = nrec + myoff;
            if (pos < 64) { rec_b[pos] = b; rec_pos[pos] = i; }
        }
        nrec += __popcll(mk);
        M = fmax(M, __shfl(pm, 63));
    }
    __syncthreads();
    int m = nrec < 64 ? nrec : 64;
    if (lane < m) {
        int r = rec_pos[lane];
        double w = w_arr[r];  // entering record r == accepting it
        int last = r;
        int hi = s0 + BLK_STEPS;
#pragma unroll 4
        for (int i = r + 1; i < hi; ++i) {
            double bb = b_arr[i];
            if (bb > w) { w = w_arr[i]; last = i; }
        }
        recb_g[bl * 64 + lane] = rec_b[lane];
        outw_g[bl * 64 + lane] = w;
        outlast_g[bl * 64 + lane] = last;
    }
    if (lane == 0) meta[bl] = nrec;
}

// ---------------- kernel C: sequential composition over blocks (1 wave, 8-deep prefetch) ----------------
__global__ __launch_bounds__(64) void k_compose(const double* __restrict__ w_arr,
                                                const double* __restrict__ b_arr,
                                                const double* __restrict__ recb_g,
                                                const double* __restrict__ outw_g,
                                                const int* __restrict__ outlast_g,
                                                const int* __restrict__ meta,
                                                double* __restrict__ bin_w,
                                                int* __restrict__ bin_last) {
    int lane = threadIdx.x;
    // idx0 = first non-gold row (b > -inf)
    int idx0 = 0;
    for (int base = 0; base < T_CHAIN; base += 64) {
        double b = b_arr[base + lane];
        unsigned long long mk = __ballot(b > neg_inf_d());
        if (mk) { idx0 = base + __ffsll((unsigned long long)mk) - 1; break; }
    }
    double wstate = w_arr[0];  // ref: w_last = w[0] regardless of idx0
    int last = idx0;

    double pb[8], pw[8];
    int pl[8], pmv[8];
#pragma unroll
    for (int ph = 0; ph < 8; ++ph) {
        pb[ph] = recb_g[ph * 64 + lane];
        pw[ph] = outw_g[ph * 64 + lane];
        pl[ph] = outlast_g[ph * 64 + lane];
        pmv[ph] = meta[ph];
    }
    for (int base = 0; base < NB; base += 8) {
#pragma unroll
        for (int ph = 0; ph < 8; ++ph) {
            int bl = base + ph;
            if (lane == 0) { bin_w[bl] = wstate; bin_last[bl] = last; }  // incoming state
            int mr = pmv[ph];
            int m = mr < 64 ? mr : 64;
            if (mr > 64) {
                // record-list overflow fallback: serial wave replay (practically never taken)
                for (int c = 0; c < BLK_STEPS / 64; ++c) {
                    int ib = bl * BLK_STEPS + c * 64;
                    int i = ib + lane;
                    double b = b_arr[i];
                    if (i == 0) b = neg_inf_d();
                    double wv2 = w_arr[i];
                    unsigned long long excl = 0;
                    while (true) {
                        unsigned long long cand = __ballot(b > wstate) & ~excl;
                        if (!cand) break;
                        int rel = __ffsll(cand) - 1;
                        excl = ((1ull << rel) << 1) - 1ull;
                        wstate = __shfl(wv2, rel);
                        last = ib + rel;
                    }
                }
            } else {
                unsigned long long mk = __ballot((lane < m) && (pb[ph] > wstate));
                if (mk) {  // first record with b > w_in is the first accept
                    int j = __ffsll(mk) - 1;
                    wstate = __shfl(pw[ph], j);
                    last = __shfl(pl[ph], j);
                }
            }
            int nb2 = bl + 8;  // 8-deep prefetch ring (static addresses)
            if (nb2 < NB) {
                pb[ph] = recb_g[nb2 * 64 + lane];
                pw[ph] = outw_g[nb2 * 64 + lane];
                pl[ph] = outlast_g[nb2 * 64 + lane];
                pmv[ph] = meta[nb2];
            }
        }
    }
}

// ---------------- kernel D: per-block replay + output emit ----------------
__global__ __launch_bounds__(256) void k_emit(const float* __restrict__ rand_u,
                                              const double* __restrict__ w_arr,
                                              const double* __restrict__ b_arr,
                                              const double* __restrict__ bin_w,
                                              const int* __restrict__ bin_last,
                                              int* __restrict__ out) {
    __shared__ int ldsL[OUT_PER_BLK];
    int bl = blockIdx.x;
    int lane = threadIdx.x & 63;
    int wv = threadIdx.x >> 6;
    int s0 = bl * BLK_STEPS;
    if (wv == 0) {
        double w = bin_w[bl];
        int last = bin_last[bl];
        for (int c = 0; c < BLK_STEPS / 64; ++c) {
            int ib = s0 + c * 64;
            int i = ib + lane;
            double b = b_arr[i];
            if (i == 0) b = neg_inf_d();
            double wv2 = w_arr[i];
            unsigned long long accmask = 0, excl = 0;
            while (true) {  // iterate accepts within this 64-step chunk (usually 0)
                unsigned long long cand = __ballot(b > w) & ~excl;
                if (!cand) break;
                int rel = __ffsll(cand) - 1;
                excl = ((1ull << rel) << 1) - 1ull;  // decisions <= rel are final
                accmask |= (1ull << rel);
                w = __shfl(wv2, rel);
            }
            unsigned long long upto = accmask & (((1ull << lane) << 1) - 1ull);  // bits 0..lane
            int Lp = upto ? (ib + 63 - __clzll(upto)) : last;
            int r = c * 64 + lane;
            if (r % 10 == 9) ldsL[(r - 9) / 10] = Lp;  // chain[i] sampled at i%10==9
            if (accmask) last = ib + 63 - __clzll(accmask);
        }
    }
    __syncthreads();
    int prevL = -1;
    int perm = 0;
    for (int t = wv * 64; t < wv * 64 + 64; ++t) {
        int L = ldsL[t];
        if (L != prevL) {  // dedup: L constant over long stretches (~10^2 accepts total)
            perm = wave_sort_row(rand_u + (size_t)L * 64, lane);
            prevL = L;
        }
        out[((size_t)(bl * OUT_PER_BLK + t)) * 64 + lane] = perm;
    }
}

extern "C" void kernel_launch(void* const* d_in, const int* in_sizes, int n_in,
                              void* d_out, int out_size, void* d_ws, size_t ws_size,
                              hipStream_t stream) {
    const float* rand_u = (const float*)d_in[0];
    const float* u      = (const float*)d_in[1];
    const float* bigram = (const float*)d_in[2];
    const float* startv = (const float*)d_in[3];
    const float* endv   = (const float*)d_in[4];
    int* out = (int*)d_out;

    char* ws = (char*)d_ws;
    const size_t SZ_T8 = (size_t)T_CHAIN * 8;  // 5,242,880
    double* w_arr   = (double*)(ws);
    double* b_arr   = (double*)(ws + SZ_T8);
    double* recb    = (double*)(ws + 2 * SZ_T8);                    // NB*64*8
    double* outw    = (double*)(ws + 2 * SZ_T8 + 131072);           // NB*64*8
    int*    outlast = (int*)   (ws + 2 * SZ_T8 + 262144);           // NB*64*4
    int*    meta    = (int*)   (ws + 2 * SZ_T8 + 327680);           // NB*4
    double* bin_w   = (double*)(ws + 2 * SZ_T8 + 328704);           // NB*8
    int*    bin_last= (int*)   (ws + 2 * SZ_T8 + 330752);           // NB*4

    k_rows<<<T_CHAIN / 4, 256, 0, stream>>>(rand_u, bigram, startv, endv, u, w_arr, b_arr);
    k_records<<<NB, 64, 0, stream>>>(w_arr, b_arr, recb, outw, outlast, meta);
    k_compose<<<1, 64, 0, stream>>>(w_arr, b_arr, recb, outw, outlast, meta, bin_w, bin_last);
    k_emit<<<NB, 256, 0, stream>>>(rand_u, w_arr, b_arr, bin_w, bin_last, out);
}

// Round 3
// 639.882 us; speedup vs baseline: 1.5352x; 1.4134x over previous
//
#include <hip/hip_runtime.h>
#include <math.h>

#define T_CHAIN 655360
#define BLK_STEPS 2560
#define NB (T_CHAIN / BLK_STEPS)          // 256
#define NCHUNK (BLK_STEPS / 64)           // 40
#define STEP_N 10
#define OUT_PER_BLK (BLK_STEPS / STEP_N)  // 256

__device__ __forceinline__ double neg_inf_d() {
    return __longlong_as_double((long long)0xFFF0000000000000LL);
}

// ---- lane-XOR transport: DPP for 1/2 (VALU pipe), ds_swizzle for 4/8/16, shfl for 32 ----
template<int J>
__device__ __forceinline__ unsigned xor_u32(unsigned v) {
    if constexpr (J == 1)
        return (unsigned)__builtin_amdgcn_update_dpp(0, (int)v, 0xB1, 0xF, 0xF, true);  // quad_perm [1,0,3,2]
    else if constexpr (J == 2)
        return (unsigned)__builtin_amdgcn_update_dpp(0, (int)v, 0x4E, 0xF, 0xF, true);  // quad_perm [2,3,0,1]
    else if constexpr (J <= 16)
        return (unsigned)__builtin_amdgcn_ds_swizzle((int)v, (J << 10) | 0x1F);         // BitMode xor=J
    else
        return (unsigned)__shfl_xor((int)v, 32);
}

template<int J>
__device__ __forceinline__ unsigned long long xor_u64(unsigned long long v) {
    unsigned lo = xor_u32<J>((unsigned)v);
    unsigned hi = xor_u32<J>((unsigned)(v >> 32));
    return (((unsigned long long)hi) << 32) | lo;
}

template<int J>
__device__ __forceinline__ double dxor(double d) {  // partner's value at lane^J (bit-exact transport)
    return __longlong_as_double((long long)xor_u64<J>((unsigned long long)__double_as_longlong(d)));
}

// one bitonic compare-exchange stage on TWO independent packed u64 keys
// (takeMin lane-pattern computed once, CSE'd across both rows)
template<int K, int J>
__device__ __forceinline__ void cex2(unsigned long long& k0, unsigned long long& k1, int lane) {
    unsigned long long p0 = xor_u64<J>(k0);
    unsigned long long p1 = xor_u64<J>(k1);
    bool takeMin = (((lane & J) == 0) == ((lane & K) == 0));
    bool l0 = p0 < k0;  // keys unique -> never equal
    bool l1 = p1 < k1;
    if (l0 == takeMin) k0 = p0;
    if (l1 == takeMin) k1 = p1;
}

template<int K, int J>
__device__ __forceinline__ void cex(unsigned long long& key, int lane) {
    unsigned long long pk = xor_u64<J>(key);
    bool takeMin = (((lane & J) == 0) == ((lane & K) == 0));
    bool pless = pk < key;
    if (pless == takeMin) key = pk;
}

#define SORT_NET(CEX_STMT)                                                                 \
    CEX_STMT(2, 1)                                                                          \
    CEX_STMT(4, 2) CEX_STMT(4, 1)                                                           \
    CEX_STMT(8, 4) CEX_STMT(8, 2) CEX_STMT(8, 1)                                            \
    CEX_STMT(16, 8) CEX_STMT(16, 4) CEX_STMT(16, 2) CEX_STMT(16, 1)                         \
    CEX_STMT(32, 16) CEX_STMT(32, 8) CEX_STMT(32, 4) CEX_STMT(32, 2) CEX_STMT(32, 1)        \
    CEX_STMT(64, 32) CEX_STMT(64, 16) CEX_STMT(64, 8) CEX_STMT(64, 4) CEX_STMT(64, 2) CEX_STMT(64, 1)

// Stable ascending argsort of 64 floats held one-per-lane. rp[lane] = original index at sorted pos lane.
__device__ __forceinline__ int wave_sort_row(const float* __restrict__ xrow, int lane) {
    unsigned bits = __float_as_uint(xrow[lane]);  // positive floats: bit order == value order
    unsigned long long key = (((unsigned long long)bits) << 6) | (unsigned)lane;  // stable composite
#define S1(K, J) cex<K, J>(key, lane);
    SORT_NET(S1)
#undef S1
    return (int)(key & 63u);
}

__device__ __forceinline__ void wave_sort_row2(const float* __restrict__ x0p,
                                               const float* __restrict__ x1p,
                                               int lane, int& rp0, int& rp1) {
    unsigned b0 = __float_as_uint(x0p[lane]);
    unsigned b1 = __float_as_uint(x1p[lane]);
    unsigned long long k0 = (((unsigned long long)b0) << 6) | (unsigned)lane;
    unsigned long long k1 = (((unsigned long long)b1) << 6) | (unsigned)lane;
#define S2(K, J) cex2<K, J>(k0, k1, lane);
    SORT_NET(S2)
#undef S2
    rp0 = (int)(k0 & 63u);
    rp1 = (int)(k1 & 63u);
}

__device__ __forceinline__ void score_row(int row, int rp, int lane,
                                          const float* __restrict__ bigram,
                                          const float* __restrict__ startv,
                                          const float* __restrict__ endv,
                                          const float* __restrict__ u,
                                          double* __restrict__ w_arr,
                                          double* __restrict__ b_arr) {
    bool gold = (bool)__all(rp == lane);
    int nxt = __shfl_down(rp, 1);
    double dt = 0.0;
    if (lane < 63) dt = (double)bigram[rp * 64 + nxt];  // bigram[rp[k], rp[k+1]]
    if (lane == 0) dt += (double)startv[rp];
    if (lane == 63) dt += (double)endv[rp];
    // xor-tree reduce, SAME pairing order as prior rounds (bit-identical w)
    dt += dxor<32>(dt);
    dt += dxor<16>(dt);
    dt += dxor<8>(dt);
    dt += dxor<4>(dt);
    dt += dxor<2>(dt);
    dt += dxor<1>(dt);
    if (lane == 0) {
        w_arr[row] = dt;
        b_arr[row] = gold ? neg_inf_d() : (dt - log((double)u[row]));
        // accept(i | w_last) == (b_i > w_last); gold rows never accept
    }
}

// ---------------- kernel A: per-row sort + w + b (two rows per wave) ----------------
__global__ __launch_bounds__(256) void k_rows(const float* __restrict__ rand_u,
                                              const float* __restrict__ bigram,
                                              const float* __restrict__ startv,
                                              const float* __restrict__ endv,
                                              const float* __restrict__ u,
                                              double* __restrict__ w_arr,
                                              double* __restrict__ b_arr) {
    int lane = threadIdx.x & 63;
    int wv = threadIdx.x >> 6;
    int row0 = blockIdx.x * 8 + wv * 2;
    int row1 = row0 + 1;
    int rp0, rp1;
    wave_sort_row2(rand_u + (size_t)row0 * 64, rand_u + (size_t)row1 * 64, lane, rp0, rp1);
    score_row(row0, rp0, lane, bigram, startv, endv, u, w_arr, b_arr);
    score_row(row1, rp1, lane, bigram, startv, endv, u, w_arr, b_arr);
}

// ---------------- kernel B: records + chunk-maxes + wave-cooperative per-record replay ----------------
__global__ __launch_bounds__(256) void k_records(const double* __restrict__ w_arr,
                                                 const double* __restrict__ b_arr,
                                                 double* __restrict__ recb_g,
                                                 double* __restrict__ outw_g,
                                                 int* __restrict__ outlast_g,
                                                 int* __restrict__ meta,
                                                 double* __restrict__ cmax_g) {
    __shared__ double rec_b_s[64];
    __shared__ int rec_pos_s[64];
    __shared__ double cmax_s[NCHUNK];
    __shared__ int nrec_s;
    int tid = threadIdx.x, lane = tid & 63, wv = tid >> 6;
    int bl = blockIdx.x, s0 = bl * BLK_STEPS;

    if (wv == 0) {
        double M = neg_inf_d();
        int nrec = 0;
        for (int c = 0; c < NCHUNK; ++c) {
            int i = s0 + c * 64 + lane;
            double b = b_arr[i];
            if (i == 0) b = neg_inf_d();  // step 0 is initial state, never a proposal
            double pm = b;                 // inclusive prefix max across lanes
#pragma unroll
            for (int d = 1; d < 64; d <<= 1) {
                double o = __shfl_up(pm, d);
                if (lane >= d) pm = fmax(pm, o);
            }
            double prev = __shfl_up(pm, 1);
            double thresh = (lane == 0) ? M : fmax(M, prev);
            bool isrec = b > thresh;  // strict prefix-max record
            unsigned long long mk = __ballot(isrec);
            int off = __popcll(mk & ((1ull << lane) - 1ull));
            int pos = nrec + off;
            if (isrec && pos < 64) { rec_b_s[pos] = b; rec_pos_s[pos] = i; }
            nrec += __popcll(mk);
            double cm = __shfl(pm, 63);
            if (lane == 0) cmax_s[c] = cm;
            M = fmax(M, cm);
        }
        if (lane == 0) { nrec_s = nrec; meta[bl] = nrec; }
        if (lane < NCHUNK) cmax_g[bl * NCHUNK + lane] = cmax_s[lane];
    }
    __syncthreads();

    int nrec = nrec_s < 64 ? nrec_s : 64;
    double mycm = (lane < NCHUNK) ? cmax_s[lane] : neg_inf_d();
    for (int j = wv; j < nrec; j += 4) {   // wave wv replays record j
        int r = rec_pos_s[j];
        double w = w_arr[r];  // entering record r == accepting it
        int last = r;
        int cstart = (r + 1 - s0) >> 6;  // first chunk containing r+1
        while (true) {
            unsigned long long cand = __ballot(lane >= cstart && mycm > w);
            if (!cand) break;
            int c = __ffsll(cand) - 1;   // first chunk that could contain an accept
            int i = s0 + c * 64 + lane;
            double b = b_arr[i];
            if (i <= r || i == 0) b = neg_inf_d();
            double wv2 = w_arr[i];
            unsigned long long excl = 0;
            while (true) {
                unsigned long long a = __ballot(b > w) & ~excl;
                if (!a) break;
                int rel = __ffsll(a) - 1;
                excl = ((1ull << rel) << 1) - 1ull;
                w = __shfl(wv2, rel);
                last = s0 + c * 64 + rel;
            }
            cstart = c + 1;
        }
        if (lane == 0) {
            recb_g[bl * 64 + j] = rec_b_s[j];
            outw_g[bl * 64 + j] = w;
            outlast_g[bl * 64 + j] = last;
        }
    }
}

// ---------------- kernel C: sequential composition over blocks (1 wave, 8-deep prefetch) ----------------
__global__ __launch_bounds__(64) void k_compose(const double* __restrict__ w_arr,
                                                const double* __restrict__ b_arr,
                                                const double* __restrict__ recb_g,
                                                const double* __restrict__ outw_g,
                                                const int* __restrict__ outlast_g,
                                                const int* __restrict__ meta,
                                                double* __restrict__ bin_w,
                                                int* __restrict__ bin_last) {
    int lane = threadIdx.x;
    // idx0 = first non-gold row (b > -inf)
    int idx0 = 0;
    for (int base = 0; base < T_CHAIN; base += 64) {
        double b = b_arr[base + lane];
        unsigned long long mk = __ballot(b > neg_inf_d());
        if (mk) { idx0 = base + __ffsll((unsigned long long)mk) - 1; break; }
    }
    double wstate = w_arr[0];  // ref: w_last = w[0] regardless of idx0
    int last = idx0;

    double pb[8], pw[8];
    int pl[8], pmv[8];
#pragma unroll
    for (int ph = 0; ph < 8; ++ph) {
        pb[ph] = recb_g[ph * 64 + lane];
        pw[ph] = outw_g[ph * 64 + lane];
        pl[ph] = outlast_g[ph * 64 + lane];
        pmv[ph] = meta[ph];
    }
    for (int base = 0; base < NB; base += 8) {
#pragma unroll
        for (int ph = 0; ph < 8; ++ph) {
            int bl = base + ph;
            if (lane == 0) { bin_w[bl] = wstate; bin_last[bl] = last; }  // incoming state
            int mr = pmv[ph];
            int m = mr < 64 ? mr : 64;
            if (mr > 64) {
                // record-list overflow fallback: serial wave replay (practically never taken)
                for (int c = 0; c < BLK_STEPS / 64; ++c) {
                    int ib = bl * BLK_STEPS + c * 64;
                    int i = ib + lane;
                    double b = b_arr[i];
                    if (i == 0) b = neg_inf_d();
                    double wv2 = w_arr[i];
                    unsigned long long excl = 0;
                    while (true) {
                        unsigned long long cand = __ballot(b > wstate) & ~excl;
                        if (!cand) break;
                        int rel = __ffsll(cand) - 1;
                        excl = ((1ull << rel) << 1) - 1ull;
                        wstate = __shfl(wv2, rel);
                        last = ib + rel;
                    }
                }
            } else {
                unsigned long long mk = __ballot((lane < m) && (pb[ph] > wstate));
                if (mk) {  // first record with b > w_in is the first accept
                    int j = __ffsll(mk) - 1;
                    wstate = __shfl(pw[ph], j);
                    last = __shfl(pl[ph], j);
                }
            }
            int nb2 = bl + 8;  // 8-deep prefetch ring (static addresses)
            if (nb2 < NB) {
                pb[ph] = recb_g[nb2 * 64 + lane];
                pw[ph] = outw_g[nb2 * 64 + lane];
                pl[ph] = outlast_g[nb2 * 64 + lane];
                pmv[ph] = meta[nb2];
            }
        }
    }
}

// ---------------- kernel D: per-block replay (chunk-skip) + output emit ----------------
__global__ __launch_bounds__(256) void k_emit(const float* __restrict__ rand_u,
                                              const double* __restrict__ w_arr,
                                              const double* __restrict__ b_arr,
                                              const double* __restrict__ bin_w,
                                              const int* __restrict__ bin_last,
                                              const double* __restrict__ cmax_g,
                                              int* __restrict__ out) {
    __shared__ int ldsL[OUT_PER_BLK];
    __shared__ unsigned long long accm_s[NCHUNK];
    __shared__ int lastStart_s[NCHUNK];
    int tid = threadIdx.x, lane = tid & 63, wv = tid >> 6;
    int bl = blockIdx.x, s0 = bl * BLK_STEPS;

    if (wv == 0) {
        double w = bin_w[bl];
        int last = bin_last[bl];
        double mycm = (lane < NCHUNK) ? cmax_g[bl * NCHUNK + lane] : neg_inf_d();
        for (int c = 0; c < NCHUNK; ++c) {
            if (lane == 0) lastStart_s[c] = last;
            double cm = __shfl(mycm, c);
            unsigned long long accmask = 0;
            if (cm > w) {  // chunk can contain an accept
                int i = s0 + c * 64 + lane;
                double b = b_arr[i];
                if (i == 0) b = neg_inf_d();
                double wv2 = w_arr[i];
                unsigned long long excl = 0;
                while (true) {
                    unsigned long long a = __ballot(b > w) & ~excl;
                    if (!a) break;
                    int rel = __ffsll(a) - 1;
                    excl = ((1ull << rel) << 1) - 1ull;  // decisions <= rel final
                    accmask |= (1ull << rel);
                    w = __shfl(wv2, rel);
                }
                if (accmask) last = s0 + c * 64 + 63 - __clzll(accmask);
            }
            if (lane == 0) accm_s[c] = accmask;
        }
    }
    __syncthreads();
    {
        int t = tid;  // 256 sampled outputs per block
        int r = 10 * t + 9;
        int c = r >> 6, rel = r & 63;
        unsigned long long m = accm_s[c] & (((1ull << rel) << 1) - 1ull);  // accepts <= rel
        ldsL[t] = m ? (s0 + c * 64 + 63 - __clzll(m)) : lastStart_s[c];
    }
    __syncthreads();

    int prevL = -1;
    int perm = 0;
    for (int t = wv * 64; t < wv * 64 + 64; ++t) {
        int L = ldsL[t];
        if (L != prevL) {  // dedup: L constant over long stretches (accepts rare)
            perm = wave_sort_row(rand_u + (size_t)L * 64, lane);
            prevL = L;
        }
        out[((size_t)(bl * OUT_PER_BLK + t)) * 64 + lane] = perm;
    }
}

extern "C" void kernel_launch(void* const* d_in, const int* in_sizes, int n_in,
                              void* d_out, int out_size, void* d_ws, size_t ws_size,
                              hipStream_t stream) {
    const float* rand_u = (const float*)d_in[0];
    const float* u      = (const float*)d_in[1];
    const float* bigram = (const float*)d_in[2];
    const float* startv = (const float*)d_in[3];
    const float* endv   = (const float*)d_in[4];
    int* out = (int*)d_out;

    char* ws = (char*)d_ws;
    const size_t SZ_T8 = (size_t)T_CHAIN * 8;  // 5,242,880
    double* w_arr   = (double*)(ws);
    double* b_arr   = (double*)(ws + SZ_T8);
    double* recb    = (double*)(ws + 2 * SZ_T8);                    // NB*64*8
    double* outw    = (double*)(ws + 2 * SZ_T8 + 131072);           // NB*64*8
    int*    outlast = (int*)   (ws + 2 * SZ_T8 + 262144);           // NB*64*4
    int*    meta    = (int*)   (ws + 2 * SZ_T8 + 327680);           // NB*4
    double* bin_w   = (double*)(ws + 2 * SZ_T8 + 328704);           // NB*8
    int*    bin_last= (int*)   (ws + 2 * SZ_T8 + 330752);           // NB*4
    double* cmax_g  = (double*)(ws + 2 * SZ_T8 + 331776);           // NB*NCHUNK*8 = 81920

    k_rows<<<T_CHAIN / 8, 256, 0, stream>>>(rand_u, bigram, startv, endv, u, w_arr, b_arr);
    k_records<<<NB, 256, 0, stream>>>(w_arr, b_arr, recb, outw, outlast, meta, cmax_g);
    k_compose<<<1, 64, 0, stream>>>(w_arr, b_arr, recb, outw, outlast, meta, bin_w, bin_last);
    k_emit<<<NB, 256, 0, stream>>>(rand_u, w_arr, b_arr, bin_w, bin_last, cmax_g, out);
}

// Round 6
// 466.249 us; speedup vs baseline: 2.1069x; 1.3724x over previous
//
#include <hip/hip_runtime.h>
#include <math.h>

#define T_CHAIN 655360
#define BLK_STEPS 2560
#define NB (T_CHAIN / BLK_STEPS)          // 256
#define NCHUNK (BLK_STEPS / 64)           // 40
#define STEP_N 10
#define OUT_PER_BLK (BLK_STEPS / STEP_N)  // 256

typedef unsigned long long u64;

__device__ __forceinline__ double neg_inf_d() {
    return __longlong_as_double((long long)0xFFF0000000000000LL);
}

// ---- lane-XOR transport for the (rare) wave-level sort in k_emit ----
template<int J>
__device__ __forceinline__ unsigned xor_u32(unsigned v) {
    if constexpr (J == 1)
        return (unsigned)__builtin_amdgcn_update_dpp(0, (int)v, 0xB1, 0xF, 0xF, true);
    else if constexpr (J == 2)
        return (unsigned)__builtin_amdgcn_update_dpp(0, (int)v, 0x4E, 0xF, 0xF, true);
    else if constexpr (J <= 16)
        return (unsigned)__builtin_amdgcn_ds_swizzle((int)v, (J << 10) | 0x1F);
    else
        return (unsigned)__shfl_xor((int)v, 32);
}

template<int J>
__device__ __forceinline__ u64 xor_u64(u64 v) {
    unsigned lo = xor_u32<J>((unsigned)v);
    unsigned hi = xor_u32<J>((unsigned)(v >> 32));
    return (((u64)hi) << 32) | lo;
}

template<int K, int J>
__device__ __forceinline__ void cex(u64& key, int lane) {
    u64 pk = xor_u64<J>(key);
    bool takeMin = (((lane & J) == 0) == ((lane & K) == 0));
    bool pless = pk < key;
    if (pless == takeMin) key = pk;
}

#define SORT_NET(CEX_STMT)                                                                 \
    CEX_STMT(2, 1)                                                                          \
    CEX_STMT(4, 2) CEX_STMT(4, 1)                                                           \
    CEX_STMT(8, 4) CEX_STMT(8, 2) CEX_STMT(8, 1)                                            \
    CEX_STMT(16, 8) CEX_STMT(16, 4) CEX_STMT(16, 2) CEX_STMT(16, 1)                         \
    CEX_STMT(32, 16) CEX_STMT(32, 8) CEX_STMT(32, 4) CEX_STMT(32, 2) CEX_STMT(32, 1)        \
    CEX_STMT(64, 32) CEX_STMT(64, 16) CEX_STMT(64, 8) CEX_STMT(64, 4) CEX_STMT(64, 2) CEX_STMT(64, 1)

// wave-level stable argsort (used only for rare dedup'd sorts in k_emit)
__device__ __forceinline__ int wave_sort_row(const float* __restrict__ xrow, int lane) {
    unsigned bits = __float_as_uint(xrow[lane]);
    u64 key = (((u64)bits) << 6) | (unsigned)lane;
#define S1(K, J) cex<K, J>(key, lane);
    SORT_NET(S1)
#undef S1
    return (int)(key & 63u);
}

// ---------------- kernel A: thread-per-row register bitonic + LDS-bigram score ----------------
__global__ __launch_bounds__(256) void k_rows(const float* __restrict__ rand_u,
                                              const float* __restrict__ bigram,
                                              const float* __restrict__ startv,
                                              const float* __restrict__ endv,
                                              const float* __restrict__ u,
                                              double* __restrict__ w_arr,
                                              double* __restrict__ b_arr) {
    __shared__ float bg_s[64 * 64];   // 16 KB
    __shared__ float st_s[64];
    __shared__ float en_s[64];
    int tid = threadIdx.x;
    {   // stage bigram + unary terms (vectorized, once per block)
        const float4* src = (const float4*)bigram;
        float4* dst = (float4*)bg_s;
#pragma unroll
        for (int q = 0; q < 4; ++q) dst[tid + q * 256] = src[tid + q * 256];
        if (tid < 64) { st_s[tid] = startv[tid]; en_s[tid] = endv[tid]; }
    }
    __syncthreads();

    int row = blockIdx.x * 256 + tid;
    // load this row's 64 floats; key = (bits<<32) | elem_idx  (stable composite, zero-cost pack)
    u64 key[64];
    {
        const float4* rp4 = (const float4*)(rand_u + (size_t)row * 64);
#pragma unroll
        for (int q = 0; q < 16; ++q) {
            float4 v = rp4[q];
            key[4 * q + 0] = (((u64)__float_as_uint(v.x)) << 32) | (unsigned)(4 * q + 0);
            key[4 * q + 1] = (((u64)__float_as_uint(v.y)) << 32) | (unsigned)(4 * q + 1);
            key[4 * q + 2] = (((u64)__float_as_uint(v.z)) << 32) | (unsigned)(4 * q + 2);
            key[4 * q + 3] = (((u64)__float_as_uint(v.w)) << 32) | (unsigned)(4 * q + 3);
        }
    }
    // in-register bitonic sort, ascending; all indices compile-time constant
#pragma unroll
    for (int k = 2; k <= 64; k <<= 1) {
#pragma unroll
        for (int j = k >> 1; j > 0; j >>= 1) {
#pragma unroll
            for (int i = 0; i < 64; ++i) {
                int l = i ^ j;
                if (l > i) {
                    bool up = ((i & k) == 0);
                    u64 a = key[i], b = key[l];
                    bool sw = up ? (a > b) : (a < b);
                    key[i] = sw ? b : a;
                    key[l] = sw ? a : b;
                }
            }
        }
    }
    // gold check: rp[i] == i for all i
    unsigned acc = 0;
#pragma unroll
    for (int i = 0; i < 64; ++i) acc |= ((unsigned)key[i]) ^ (unsigned)i;
    bool gold = (acc == 0);
    // score: start + sum bigram[rp[j], rp[j+1]] + end   (f64 accumulate, 2-way ILP)
    double s0 = (double)st_s[(unsigned)key[0]];
    double s1 = (double)en_s[(unsigned)key[63]];
#pragma unroll
    for (int j = 0; j < 63; j += 2) {
        s0 += (double)bg_s[((unsigned)key[j] << 6) | (unsigned)key[j + 1]];
        if (j + 2 < 64)
            s1 += (j + 2 < 63) ? (double)bg_s[((unsigned)key[j + 1] << 6) | (unsigned)key[j + 2]] : 0.0;
    }
    // the j-loop covers even-j transitions in s0, odd-j transitions in s1: all 63 exactly once
    double dt = s0 + s1;
    w_arr[row] = dt;
    b_arr[row] = gold ? neg_inf_d() : (dt - log((double)u[row]));
}

// ---------------- kernel B: records (4-wave parallel) + chunk maxes + cooperative replay ----------------
__global__ __launch_bounds__(256) void k_records(const double* __restrict__ w_arr,
                                                 const double* __restrict__ b_arr,
                                                 double* __restrict__ recb_g,
                                                 double* __restrict__ outw_g,
                                                 int* __restrict__ outlast_g,
                                                 int* __restrict__ meta,
                                                 double* __restrict__ cmax_g) {
    __shared__ double cand_b[4][64];
    __shared__ int cand_pos[4][64];
    __shared__ int nf_s[4];
    __shared__ double cmax_s[NCHUNK];
    __shared__ double rec_b_s[64];
    __shared__ int rec_pos_s[64];
    __shared__ int ovfl_s;
    int tid = threadIdx.x, lane = tid & 63, wv = tid >> 6;
    int bl = blockIdx.x, s0 = bl * BLK_STEPS;
    if (tid == 0) ovfl_s = 0;

    // phase 1: each wave scans 10 chunks, finds LOCAL prefix-max records
    double bb[10];
#pragma unroll
    for (int kq = 0; kq < 10; ++kq) {
        int i = s0 + (wv * 10 + kq) * 64 + lane;
        double b = b_arr[i];
        bb[kq] = (i == 0) ? neg_inf_d() : b;   // step 0 = initial state, never a proposal
    }
    double M = neg_inf_d();
    int nl = 0;
#pragma unroll
    for (int kq = 0; kq < 10; ++kq) {
        int c = wv * 10 + kq;
        double b = bb[kq];
        double pm = b;
#pragma unroll
        for (int d = 1; d < 64; d <<= 1) {
            double o = __shfl_up(pm, d);
            if (lane >= d) pm = fmax(pm, o);
        }
        double prev = __shfl_up(pm, 1);
        double thr = (lane == 0) ? M : fmax(M, prev);
        bool isc = b > thr;
        u64 mk = __ballot(isc);
        int off = __popcll(mk & ((1ull << lane) - 1ull));
        int pos = nl + off;
        if (isc && pos < 64) { cand_b[wv][pos] = b; cand_pos[wv][pos] = s0 + c * 64 + lane; }
        nl += __popcll(mk);
        double cm = __shfl(pm, 63);
        if (lane == 0) cmax_s[c] = cm;
        M = fmax(M, cm);
    }
    if (nl > 64 && lane == 0) ovfl_s = 1;
    int nl_c = nl < 64 ? nl : 64;
    __syncthreads();
    if (tid < NCHUNK) cmax_g[bl * NCHUNK + tid] = cmax_s[tid];

    // phase 1b: filter each wave's candidates by M_in = max cmax of all earlier chunks
    double v = (lane < wv * 10) ? cmax_s[lane] : neg_inf_d();
#pragma unroll
    for (int d = 1; d < 64; d <<= 1) v = fmax(v, __shfl_xor(v, d));
    double M_in = v;
    // local records have strictly increasing b -> filtered set is a suffix [j0, nl_c)
    bool pass = (lane < nl_c) && (cand_b[wv][lane] > M_in);
    u64 pmk = __ballot(pass);
    int j0 = pmk ? (__ffsll(pmk) - 1) : nl_c;
    int nf = nl_c - j0;
    if (lane == 0) nf_s[wv] = nf;
    __syncthreads();
    int base = 0, total = 0;
#pragma unroll
    for (int w2 = 0; w2 < 4; ++w2) {
        if (w2 < wv) base += nf_s[w2];
        total += nf_s[w2];
    }
    int ovfl = ovfl_s | (total > 64);
    if (!ovfl && lane < nf) {
        rec_b_s[base + lane] = cand_b[wv][j0 + lane];
        rec_pos_s[base + lane] = cand_pos[wv][j0 + lane];
    }
    if (tid == 0) meta[bl] = ovfl ? 100 : total;
    __syncthreads();
    if (ovfl) return;   // k_compose serial-replay fallback handles this block

    // phase 2: wave-cooperative replay from each record, chunk-skip via cmax
    double mycm = (lane < NCHUNK) ? cmax_s[lane] : neg_inf_d();
    for (int j = wv; j < total; j += 4) {
        int r = rec_pos_s[j];
        double w = w_arr[r];   // entering record r == accepting it
        int last = r;
        int cstart = (r + 1 - s0) >> 6;
        while (true) {
            u64 cand = __ballot(lane >= cstart && mycm > w);
            if (!cand) break;
            int c = __ffsll(cand) - 1;
            int i = s0 + c * 64 + lane;
            double b = b_arr[i];
            if (i <= r || i == 0) b = neg_inf_d();
            double wv2 = w_arr[i];
            u64 excl = 0;
            while (true) {
                u64 a = __ballot(b > w) & ~excl;
                if (!a) break;
                int rel = __ffsll(a) - 1;
                excl = ((1ull << rel) << 1) - 1ull;
                w = __shfl(wv2, rel);
                last = s0 + c * 64 + rel;
            }
            cstart = c + 1;
        }
        if (lane == 0) {
            recb_g[bl * 64 + j] = rec_b_s[j];
            outw_g[bl * 64 + j] = w;
            outlast_g[bl * 64 + j] = last;
        }
    }
}

// ---------------- kernel C: sequential composition over blocks (1 wave, 8-deep prefetch) ----------------
__global__ __launch_bounds__(64) void k_compose(const double* __restrict__ w_arr,
                                                const double* __restrict__ b_arr,
                                                const double* __restrict__ recb_g,
                                                const double* __restrict__ outw_g,
                                                const int* __restrict__ outlast_g,
                                                const int* __restrict__ meta,
                                                double* __restrict__ bin_w,
                                                int* __restrict__ bin_last) {
    int lane = threadIdx.x;
    int idx0 = 0;   // first non-gold row
    for (int base = 0; base < T_CHAIN; base += 64) {
        double b = b_arr[base + lane];
        u64 mk = __ballot(b > neg_inf_d());
        if (mk) { idx0 = base + __ffsll(mk) - 1; break; }
    }
    double wstate = w_arr[0];  // ref: w_last = w[0] regardless of idx0
    int last = idx0;

    double pb[8], pw[8];
    int pl[8], pmv[8];
#pragma unroll
    for (int ph = 0; ph < 8; ++ph) {
        pb[ph] = recb_g[ph * 64 + lane];
        pw[ph] = outw_g[ph * 64 + lane];
        pl[ph] = outlast_g[ph * 64 + lane];
        pmv[ph] = meta[ph];
    }
    for (int base = 0; base < NB; base += 8) {
#pragma unroll
        for (int ph = 0; ph < 8; ++ph) {
            int bl = base + ph;
            if (lane == 0) { bin_w[bl] = wstate; bin_last[bl] = last; }
            int mr = pmv[ph];
            int m = mr < 64 ? mr : 64;
            if (mr > 64) {
                // overflow fallback: serial wave replay
                for (int c = 0; c < NCHUNK; ++c) {
                    int ib = bl * BLK_STEPS + c * 64;
                    int i = ib + lane;
                    double b = b_arr[i];
                    if (i == 0) b = neg_inf_d();
                    double wv2 = w_arr[i];
                    u64 excl = 0;
                    while (true) {
                        u64 cand = __ballot(b > wstate) & ~excl;
                        if (!cand) break;
                        int rel = __ffsll(cand) - 1;
                        excl = ((1ull << rel) << 1) - 1ull;
                        wstate = __shfl(wv2, rel);
                        last = ib + rel;
                    }
                }
            } else {
                u64 mk = __ballot((lane < m) && (pb[ph] > wstate));
                if (mk) {
                    int j = __ffsll(mk) - 1;
                    wstate = __shfl(pw[ph], j);
                    last = __shfl(pl[ph], j);
                }
            }
            int nb2 = bl + 8;
            if (nb2 < NB) {
                pb[ph] = recb_g[nb2 * 64 + lane];
                pw[ph] = outw_g[nb2 * 64 + lane];
                pl[ph] = outlast_g[nb2 * 64 + lane];
                pmv[ph] = meta[nb2];
            }
        }
    }
}

// ---------------- kernel D: per-block replay (chunk-skip) + output emit ----------------
__global__ __launch_bounds__(256) void k_emit(const float* __restrict__ rand_u,
                                              const double* __restrict__ w_arr,
                                              const double* __restrict__ b_arr,
                                              const double* __restrict__ bin_w,
                                              const int* __restrict__ bin_last,
                                              const double* __restrict__ cmax_g,
                                              int* __restrict__ out) {
    __shared__ int ldsL[OUT_PER_BLK];
    __shared__ u64 accm_s[NCHUNK];
    __shared__ int lastStart_s[NCHUNK];
    int tid = threadIdx.x, lane = tid & 63, wv = tid >> 6;
    int bl = blockIdx.x, s0 = bl * BLK_STEPS;

    if (wv == 0) {
        double w = bin_w[bl];
        int last = bin_last[bl];
        double mycm = (lane < NCHUNK) ? cmax_g[bl * NCHUNK + lane] : neg_inf_d();
        for (int c = 0; c < NCHUNK; ++c) {
            if (lane == 0) lastStart_s[c] = last;
            double cm = __shfl(mycm, c);
            u64 accmask = 0;
            if (cm > w) {
                int i = s0 + c * 64 + lane;
                double b = b_arr[i];
                if (i == 0) b = neg_inf_d();
                double wv2 = w_arr[i];
                u64 excl = 0;
                while (true) {
                    u64 a = __ballot(b > w) & ~excl;
                    if (!a) break;
                    int rel = __ffsll(a) - 1;
                    excl = ((1ull << rel) << 1) - 1ull;
                    accmask |= (1ull << rel);
                    w = __shfl(wv2, rel);
                }
                if (accmask) last = s0 + c * 64 + 63 - __clzll(accmask);
            }
            if (lane == 0) accm_s[c] = accmask;
        }
    }
    __syncthreads();
    {
        int t = tid;
        int r = 10 * t + 9;
        int c = r >> 6, rel = r & 63;
        u64 m = accm_s[c] & (((1ull << rel) << 1) - 1ull);
        ldsL[t] = m ? (s0 + c * 64 + 63 - __clzll(m)) : lastStart_s[c];
    }
    __syncthreads();

    int prevL = -1;
    int perm = 0;
    for (int t = wv * 64; t < wv * 64 + 64; ++t) {
        int L = ldsL[t];
        if (L != prevL) {
            perm = wave_sort_row(rand_u + (size_t)L * 64, lane);
            prevL = L;
        }
        out[((size_t)(bl * OUT_PER_BLK + t)) * 64 + lane] = perm;
    }
}

extern "C" void kernel_launch(void* const* d_in, const int* in_sizes, int n_in,
                              void* d_out, int out_size, void* d_ws, size_t ws_size,
                              hipStream_t stream) {
    const float* rand_u = (const float*)d_in[0];
    const float* u      = (const float*)d_in[1];
    const float* bigram = (const float*)d_in[2];
    const float* startv = (const float*)d_in[3];
    const float* endv   = (const float*)d_in[4];
    int* out = (int*)d_out;

    char* ws = (char*)d_ws;
    const size_t SZ_T8 = (size_t)T_CHAIN * 8;  // 5,242,880
    double* w_arr   = (double*)(ws);
    double* b_arr   = (double*)(ws + SZ_T8);
    double* recb    = (double*)(ws + 2 * SZ_T8);
    double* outw    = (double*)(ws + 2 * SZ_T8 + 131072);
    int*    outlast = (int*)   (ws + 2 * SZ_T8 + 262144);
    int*    meta    = (int*)   (ws + 2 * SZ_T8 + 327680);
    double* bin_w   = (double*)(ws + 2 * SZ_T8 + 328704);
    int*    bin_last= (int*)   (ws + 2 * SZ_T8 + 330752);
    double* cmax_g  = (double*)(ws + 2 * SZ_T8 + 331776);

    k_rows<<<T_CHAIN / 256, 256, 0, stream>>>(rand_u, bigram, startv, endv, u, w_arr, b_arr);
    k_records<<<NB, 256, 0, stream>>>(w_arr, b_arr, recb, outw, outlast, meta, cmax_g);
    k_compose<<<1, 64, 0, stream>>>(w_arr, b_arr, recb, outw, outlast, meta, bin_w, bin_last);
    k_emit<<<NB, 256, 0, stream>>>(rand_u, w_arr, b_arr, bin_w, bin_last, cmax_g, out);
}

// Round 8
// 463.196 us; speedup vs baseline: 2.1208x; 1.0066x over previous
//
#include <hip/hip_runtime.h>
#include <math.h>

#define T_CHAIN 655360
#define BLK_STEPS 2560
#define NB (T_CHAIN / BLK_STEPS)          // 256
#define NCHUNK (BLK_STEPS / 64)           // 40
#define STEP_N 10
#define OUT_PER_BLK (BLK_STEPS / STEP_N)  // 256

typedef unsigned long long u64;

__device__ __forceinline__ double neg_inf_d() {
    return __longlong_as_double((long long)0xFFF0000000000000LL);
}

// ---- lane-XOR transport for the (rare) wave-level sort in k_emit ----
template<int J>
__device__ __forceinline__ unsigned xor_u32(unsigned v) {
    if constexpr (J == 1)
        return (unsigned)__builtin_amdgcn_update_dpp(0, (int)v, 0xB1, 0xF, 0xF, true);
    else if constexpr (J == 2)
        return (unsigned)__builtin_amdgcn_update_dpp(0, (int)v, 0x4E, 0xF, 0xF, true);
    else if constexpr (J <= 16)
        return (unsigned)__builtin_amdgcn_ds_swizzle((int)v, (J << 10) | 0x1F);
    else
        return (unsigned)__shfl_xor((int)v, 32);
}

template<int J>
__device__ __forceinline__ u64 xor_u64(u64 v) {
    unsigned lo = xor_u32<J>((unsigned)v);
    unsigned hi = xor_u32<J>((unsigned)(v >> 32));
    return (((u64)hi) << 32) | lo;
}

template<int K, int J>
__device__ __forceinline__ void cex(u64& key, int lane) {
    u64 pk = xor_u64<J>(key);
    bool takeMin = (((lane & J) == 0) == ((lane & K) == 0));
    bool pless = pk < key;
    if (pless == takeMin) key = pk;
}

#define SORT_NET(CEX_STMT)                                                                 \
    CEX_STMT(2, 1)                                                                          \
    CEX_STMT(4, 2) CEX_STMT(4, 1)                                                           \
    CEX_STMT(8, 4) CEX_STMT(8, 2) CEX_STMT(8, 1)                                            \
    CEX_STMT(16, 8) CEX_STMT(16, 4) CEX_STMT(16, 2) CEX_STMT(16, 1)                         \
    CEX_STMT(32, 16) CEX_STMT(32, 8) CEX_STMT(32, 4) CEX_STMT(32, 2) CEX_STMT(32, 1)        \
    CEX_STMT(64, 32) CEX_STMT(64, 16) CEX_STMT(64, 8) CEX_STMT(64, 4) CEX_STMT(64, 2) CEX_STMT(64, 1)

// wave-level stable argsort (used only for rare dedup'd sorts in k_emit)
__device__ __forceinline__ int wave_sort_row(const float* __restrict__ xrow, int lane) {
    unsigned bits = __float_as_uint(xrow[lane]);
    u64 key = (((u64)bits) << 6) | (unsigned)lane;
#define S1(K, J) cex<K, J>(key, lane);
    SORT_NET(S1)
#undef S1
    return (int)(key & 63u);
}

// ---------------- kernel A: thread-per-row register bitonic + LDS-bigram score ----------------
// __launch_bounds__(256, 1): key[64] needs 128 VGPRs live through the whole sort;
// the default occupancy target capped allocation at 92 VGPRs -> ~36 u64 AGPR spills
// (R6 counters: VGPR=92, zero scratch traffic, VALU issue 2.3x model). Cap 1 wave/EU
// -> up to 512 VGPRs -> no spill moves.
__global__ __launch_bounds__(256, 1) void k_rows(const float* __restrict__ rand_u,
                                              const float* __restrict__ bigram,
                                              const float* __restrict__ startv,
                                              const float* __restrict__ endv,
                                              const float* __restrict__ u,
                                              double* __restrict__ w_arr,
                                              double* __restrict__ b_arr) {
    __shared__ float bg_s[64 * 64];   // 16 KB
    __shared__ float st_s[64];
    __shared__ float en_s[64];
    int tid = threadIdx.x;
    {   // stage bigram + unary terms (vectorized, once per block)
        const float4* src = (const float4*)bigram;
        float4* dst = (float4*)bg_s;
#pragma unroll
        for (int q = 0; q < 4; ++q) dst[tid + q * 256] = src[tid + q * 256];
        if (tid < 64) { st_s[tid] = startv[tid]; en_s[tid] = endv[tid]; }
    }
    __syncthreads();

    int row = blockIdx.x * 256 + tid;
    // load this row's 64 floats; key = (bits<<32) | elem_idx  (stable composite, zero-cost pack)
    u64 key[64];
    {
        const float4* rp4 = (const float4*)(rand_u + (size_t)row * 64);
#pragma unroll
        for (int q = 0; q < 16; ++q) {
            float4 v = rp4[q];
            key[4 * q + 0] = (((u64)__float_as_uint(v.x)) << 32) | (unsigned)(4 * q + 0);
            key[4 * q + 1] = (((u64)__float_as_uint(v.y)) << 32) | (unsigned)(4 * q + 1);
            key[4 * q + 2] = (((u64)__float_as_uint(v.z)) << 32) | (unsigned)(4 * q + 2);
            key[4 * q + 3] = (((u64)__float_as_uint(v.w)) << 32) | (unsigned)(4 * q + 3);
        }
    }
    // in-register bitonic sort, ascending; all indices compile-time constant
#pragma unroll
    for (int k = 2; k <= 64; k <<= 1) {
#pragma unroll
        for (int j = k >> 1; j > 0; j >>= 1) {
#pragma unroll
            for (int i = 0; i < 64; ++i) {
                int l = i ^ j;
                if (l > i) {
                    bool up = ((i & k) == 0);
                    u64 a = key[i], b = key[l];
                    bool sw = up ? (a > b) : (a < b);
                    key[i] = sw ? b : a;
                    key[l] = sw ? a : b;
                }
            }
        }
    }
    // gold check: rp[i] == i for all i
    unsigned acc = 0;
#pragma unroll
    for (int i = 0; i < 64; ++i) acc |= ((unsigned)key[i]) ^ (unsigned)i;
    bool gold = (acc == 0);
    // score: start + sum bigram[rp[j], rp[j+1]] + end   (f64 accumulate, 2-way ILP)
    double s0 = (double)st_s[(unsigned)key[0]];
    double s1 = (double)en_s[(unsigned)key[63]];
#pragma unroll
    for (int j = 0; j < 63; j += 2) {
        s0 += (double)bg_s[((unsigned)key[j] << 6) | (unsigned)key[j + 1]];
        if (j + 2 < 64)
            s1 += (j + 2 < 63) ? (double)bg_s[((unsigned)key[j + 1] << 6) | (unsigned)key[j + 2]] : 0.0;
    }
    // the j-loop covers even-j transitions in s0, odd-j transitions in s1: all 63 exactly once
    double dt = s0 + s1;
    w_arr[row] = dt;
    b_arr[row] = gold ? neg_inf_d() : (dt - log((double)u[row]));
}

// ---------------- kernel B: records (4-wave parallel) + chunk maxes + cooperative replay ----------------
__global__ __launch_bounds__(256) void k_records(const double* __restrict__ w_arr,
                                                 const double* __restrict__ b_arr,
                                                 double* __restrict__ recb_g,
                                                 double* __restrict__ outw_g,
                                                 int* __restrict__ outlast_g,
                                                 int* __restrict__ meta,
                                                 double* __restrict__ cmax_g) {
    __shared__ double cand_b[4][64];
    __shared__ int cand_pos[4][64];
    __shared__ int nf_s[4];
    __shared__ double cmax_s[NCHUNK];
    __shared__ double rec_b_s[64];
    __shared__ int rec_pos_s[64];
    __shared__ int ovfl_s;
    int tid = threadIdx.x, lane = tid & 63, wv = tid >> 6;
    int bl = blockIdx.x, s0 = bl * BLK_STEPS;
    if (tid == 0) ovfl_s = 0;

    // phase 1: each wave scans 10 chunks, finds LOCAL prefix-max records
    double bb[10];
#pragma unroll
    for (int kq = 0; kq < 10; ++kq) {
        int i = s0 + (wv * 10 + kq) * 64 + lane;
        double b = b_arr[i];
        bb[kq] = (i == 0) ? neg_inf_d() : b;   // step 0 = initial state, never a proposal
    }
    double M = neg_inf_d();
    int nl = 0;
#pragma unroll
    for (int kq = 0; kq < 10; ++kq) {
        int c = wv * 10 + kq;
        double b = bb[kq];
        double pm = b;
#pragma unroll
        for (int d = 1; d < 64; d <<= 1) {
            double o = __shfl_up(pm, d);
            if (lane >= d) pm = fmax(pm, o);
        }
        double prev = __shfl_up(pm, 1);
        double thr = (lane == 0) ? M : fmax(M, prev);
        bool isc = b > thr;
        u64 mk = __ballot(isc);
        int off = __popcll(mk & ((1ull << lane) - 1ull));
        int pos = nl + off;
        if (isc && pos < 64) { cand_b[wv][pos] = b; cand_pos[wv][pos] = s0 + c * 64 + lane; }
        nl += __popcll(mk);
        double cm = __shfl(pm, 63);
        if (lane == 0) cmax_s[c] = cm;
        M = fmax(M, cm);
    }
    if (nl > 64 && lane == 0) ovfl_s = 1;
    int nl_c = nl < 64 ? nl : 64;
    __syncthreads();
    if (tid < NCHUNK) cmax_g[bl * NCHUNK + tid] = cmax_s[tid];

    // phase 1b: filter each wave's candidates by M_in = max cmax of all earlier chunks
    double v = (lane < wv * 10) ? cmax_s[lane] : neg_inf_d();
#pragma unroll
    for (int d = 1; d < 64; d <<= 1) v = fmax(v, __shfl_xor(v, d));
    double M_in = v;
    // local records have strictly increasing b -> filtered set is a suffix [j0, nl_c)
    bool pass = (lane < nl_c) && (cand_b[wv][lane] > M_in);
    u64 pmk = __ballot(pass);
    int j0 = pmk ? (__ffsll(pmk) - 1) : nl_c;
    int nf = nl_c - j0;
    if (lane == 0) nf_s[wv] = nf;
    __syncthreads();
    int base = 0, total = 0;
#pragma unroll
    for (int w2 = 0; w2 < 4; ++w2) {
        if (w2 < wv) base += nf_s[w2];
        total += nf_s[w2];
    }
    int ovfl = ovfl_s | (total > 64);
    if (!ovfl && lane < nf) {
        rec_b_s[base + lane] = cand_b[wv][j0 + lane];
        rec_pos_s[base + lane] = cand_pos[wv][j0 + lane];
    }
    if (tid == 0) meta[bl] = ovfl ? 100 : total;
    __syncthreads();
    if (ovfl) return;   // k_compose serial-replay fallback handles this block

    // phase 2: wave-cooperative replay from each record, chunk-skip via cmax
    double mycm = (lane < NCHUNK) ? cmax_s[lane] : neg_inf_d();
    for (int j = wv; j < total; j += 4) {
        int r = rec_pos_s[j];
        double w = w_arr[r];   // entering record r == accepting it
        int last = r;
        int cstart = (r + 1 - s0) >> 6;
        while (true) {
            u64 cand = __ballot(lane >= cstart && mycm > w);
            if (!cand) break;
            int c = __ffsll(cand) - 1;
            int i = s0 + c * 64 + lane;
            double b = b_arr[i];
            if (i <= r || i == 0) b = neg_inf_d();
            double wv2 = w_arr[i];
            u64 excl = 0;
            while (true) {
                u64 a = __ballot(b > w) & ~excl;
                if (!a) break;
                int rel = __ffsll(a) - 1;
                excl = ((1ull << rel) << 1) - 1ull;
                w = __shfl(wv2, rel);
                last = s0 + c * 64 + rel;
            }
            cstart = c + 1;
        }
        if (lane == 0) {
            recb_g[bl * 64 + j] = rec_b_s[j];
            outw_g[bl * 64 + j] = w;
            outlast_g[bl * 64 + j] = last;
        }
    }
}

// ---------------- kernel C: sequential composition over blocks (1 wave, 8-deep prefetch) ----------------
__global__ __launch_bounds__(64) void k_compose(const double* __restrict__ w_arr,
                                                const double* __restrict__ b_arr,
                                                const double* __restrict__ recb_g,
                                                const double* __restrict__ outw_g,
                                                const int* __restrict__ outlast_g,
                                                const int* __restrict__ meta,
                                                double* __restrict__ bin_w,
                                                int* __restrict__ bin_last) {
    int lane = threadIdx.x;
    int idx0 = 0;   // first non-gold row
    for (int base = 0; base < T_CHAIN; base += 64) {
        double b = b_arr[base + lane];
        u64 mk = __ballot(b > neg_inf_d());
        if (mk) { idx0 = base + __ffsll(mk) - 1; break; }
    }
    double wstate = w_arr[0];  // ref: w_last = w[0] regardless of idx0
    int last = idx0;

    double pb[8], pw[8];
    int pl[8], pmv[8];
#pragma unroll
    for (int ph = 0; ph < 8; ++ph) {
        pb[ph] = recb_g[ph * 64 + lane];
        pw[ph] = outw_g[ph * 64 + lane];
        pl[ph] = outlast_g[ph * 64 + lane];
        pmv[ph] = meta[ph];
    }
    for (int base = 0; base < NB; base += 8) {
#pragma unroll
        for (int ph = 0; ph < 8; ++ph) {
            int bl = base + ph;
            if (lane == 0) { bin_w[bl] = wstate; bin_last[bl] = last; }
            int mr = pmv[ph];
            int m = mr < 64 ? mr : 64;
            if (mr > 64) {
                // overflow fallback: serial wave replay
                for (int c = 0; c < NCHUNK; ++c) {
                    int ib = bl * BLK_STEPS + c * 64;
                    int i = ib + lane;
                    double b = b_arr[i];
                    if (i == 0) b = neg_inf_d();
                    double wv2 = w_arr[i];
                    u64 excl = 0;
                    while (true) {
                        u64 cand = __ballot(b > wstate) & ~excl;
                        if (!cand) break;
                        int rel = __ffsll(cand) - 1;
                        excl = ((1ull << rel) << 1) - 1ull;
                        wstate = __shfl(wv2, rel);
                        last = ib + rel;
                    }
                }
            } else {
                u64 mk = __ballot((lane < m) && (pb[ph] > wstate));
                if (mk) {
                    int j = __ffsll(mk) - 1;
                    wstate = __shfl(pw[ph], j);
                    last = __shfl(pl[ph], j);
                }
            }
            int nb2 = bl + 8;
            if (nb2 < NB) {
                pb[ph] = recb_g[nb2 * 64 + lane];
                pw[ph] = outw_g[nb2 * 64 + lane];
                pl[ph] = outlast_g[nb2 * 64 + lane];
                pmv[ph] = meta[nb2];
            }
        }
    }
}

// ---------------- kernel D: per-block replay (chunk-skip) + output emit ----------------
__global__ __launch_bounds__(256) void k_emit(const float* __restrict__ rand_u,
                                              const double* __restrict__ w_arr,
                                              const double* __restrict__ b_arr,
                                              const double* __restrict__ bin_w,
                                              const int* __restrict__ bin_last,
                                              const double* __restrict__ cmax_g,
                                              int* __restrict__ out) {
    __shared__ int ldsL[OUT_PER_BLK];
    __shared__ u64 accm_s[NCHUNK];
    __shared__ int lastStart_s[NCHUNK];
    int tid = threadIdx.x, lane = tid & 63, wv = tid >> 6;
    int bl = blockIdx.x, s0 = bl * BLK_STEPS;

    if (wv == 0) {
        double w = bin_w[bl];
        int last = bin_last[bl];
        double mycm = (lane < NCHUNK) ? cmax_g[bl * NCHUNK + lane] : neg_inf_d();
        for (int c = 0; c < NCHUNK; ++c) {
            if (lane == 0) lastStart_s[c] = last;
            double cm = __shfl(mycm, c);
            u64 accmask = 0;
            if (cm > w) {
                int i = s0 + c * 64 + lane;
                double b = b_arr[i];
                if (i == 0) b = neg_inf_d();
                double wv2 = w_arr[i];
                u64 excl = 0;
                while (true) {
                    u64 a = __ballot(b > w) & ~excl;
                    if (!a) break;
                    int rel = __ffsll(a) - 1;
                    excl = ((1ull << rel) << 1) - 1ull;
                    accmask |= (1ull << rel);
                    w = __shfl(wv2, rel);
                }
                if (accmask) last = s0 + c * 64 + 63 - __clzll(accmask);
            }
            if (lane == 0) accm_s[c] = accmask;
        }
    }
    __syncthreads();
    {
        int t = tid;
        int r = 10 * t + 9;
        int c = r >> 6, rel = r & 63;
        u64 m = accm_s[c] & (((1ull << rel) << 1) - 1ull);
        ldsL[t] = m ? (s0 + c * 64 + 63 - __clzll(m)) : lastStart_s[c];
    }
    __syncthreads();

    int prevL = -1;
    int perm = 0;
    for (int t = wv * 64; t < wv * 64 + 64; ++t) {
        int L = ldsL[t];
        if (L != prevL) {
            perm = wave_sort_row(rand_u + (size_t)L * 64, lane);
            prevL = L;
        }
        out[((size_t)(bl * OUT_PER_BLK + t)) * 64 + lane] = perm;
    }
}

extern "C" void kernel_launch(void* const* d_in, const int* in_sizes, int n_in,
                              void* d_out, int out_size, void* d_ws, size_t ws_size,
                              hipStream_t stream) {
    const float* rand_u = (const float*)d_in[0];
    const float* u      = (const float*)d_in[1];
    const float* bigram = (const float*)d_in[2];
    const float* startv = (const float*)d_in[3];
    const float* endv   = (const float*)d_in[4];
    int* out = (int*)d_out;

    char* ws = (char*)d_ws;
    const size_t SZ_T8 = (size_t)T_CHAIN * 8;  // 5,242,880
    double* w_arr   = (double*)(ws);
    double* b_arr   = (double*)(ws + SZ_T8);
    double* recb    = (double*)(ws + 2 * SZ_T8);
    double* outw    = (double*)(ws + 2 * SZ_T8 + 131072);
    int*    outlast = (int*)   (ws + 2 * SZ_T8 + 262144);
    int*    meta    = (int*)   (ws + 2 * SZ_T8 + 327680);
    double* bin_w   = (double*)(ws + 2 * SZ_T8 + 328704);
    int*    bin_last= (int*)   (ws + 2 * SZ_T8 + 330752);
    double* cmax_g  = (double*)(ws + 2 * SZ_T8 + 331776);

    k_rows<<<T_CHAIN / 256, 256, 0, stream>>>(rand_u, bigram, startv, endv, u, w_arr, b_arr);
    k_records<<<NB, 256, 0, stream>>>(w_arr, b_arr, recb, outw, outlast, meta, cmax_g);
    k_compose<<<1, 64, 0, stream>>>(w_arr, b_arr, recb, outw, outlast, meta, bin_w, bin_last);
    k_emit<<<NB, 256, 0, stream>>>(rand_u, w_arr, b_arr, bin_w, bin_last, cmax_g, out);
}